// Round 3
// baseline (512.125 us; speedup 1.0000x reference)
//
#include <hip/hip_runtime.h>
#include <math.h>

#define TSTEPS 512
#define RPB 8
#define L2E  1.4426950408889634f
#define L2E2 2.8853900817779268f   // 2*log2(e)

typedef __attribute__((ext_vector_type(4))) short short4v;
typedef __attribute__((ext_vector_type(8))) short short8;
typedef __attribute__((ext_vector_type(4))) float f32x4;
typedef __bf16 bf16x8 __attribute__((ext_vector_type(8)));

__device__ __forceinline__ short f2bf(float f) {            // RNE float->bf16
    union { float f; unsigned u; } v; v.f = f;
    return (short)((v.u + 0x7FFFu + ((v.u >> 16) & 1u)) >> 16);
}
__device__ __forceinline__ unsigned pkbf(float lo, float hi) {  // HW RNE pack
    unsigned r;
    asm("v_cvt_pk_bf16_f32 %0, %1, %2" : "=v"(r) : "v"(lo), "v"(hi));
    return r;
}
__device__ __forceinline__ float rcp_f(float x) { return __builtin_amdgcn_rcpf(x); }
__device__ __forceinline__ float ex2(float x)   { return __builtin_amdgcn_exp2f(x); }
__device__ __forceinline__ float sigm_p(float v) { return rcp_f(1.0f + ex2(-v)); }   // v = x*log2e
__device__ __forceinline__ float tanh_p(float v) {                                    // v = x*2log2e
    return fmaf(-2.0f, rcp_f(1.0f + ex2(v)), 1.0f);        // 1 - 2/(1+e^{2x})
}
__device__ __forceinline__ f32x4 mfma16(bf16x8 a, bf16x8 b, f32x4 c) {
    return __builtin_amdgcn_mfma_f32_16x16x32_bf16(a, b, c, 0, 0, 0);
}
// quad_perm DPP: 0xB1 = lane^1, 0x4E = lane^2 (within each 4-lane quad)
template<int CTRL>
__device__ __forceinline__ float dpp4(float v) {
    return __builtin_bit_cast(float,
        __builtin_amdgcn_mov_dpp(__builtin_bit_cast(int, v), CTRL, 0xF, 0xF, true));
}

// 256 blocks x 256 threads (4 waves, 1/SIMD). Both layers merged into ONE
// 16x16 MFMA tile via block-diagonal K-packing (K=224), A rows as before:
//   rows 0-7  = [x_t (32) | h0^{t-1} (64) | 0 (128)]        -> L0 step t
//   rows 8-15 = [0 (96)   | h0^{t-1} (64) | h1^{t-2} (64)]  -> L1 step t-1
// THIS ROUND: C columns are gate-interleaved per 4-cell sub-tile. Per wave,
// sub-tile t (t=0..3) covers cells 16*wl + 4t..4t+3: col n = gate (n&3) of
// cell 16*wl + 4t + (n>>2). Sub-tile t's activations depend only on its own
// 7 MFMAs -> acts(t) overlap MFMA issue of tiles t+1.. (separate HW pipes;
// previously acts needed all 28 MFMAs and ran strictly after). A 4x4 quad
// transpose (DPP, validated in an earlier round) gives each lane all 4 gates
// of one (row, cell); c stays fp32 in regs (4 cells x 1 row per lane).
#define ACT_STORE(Acc, cc, OFF, FRZ) do {                               \
    const float hv_ = actTile(Acc, cc, FRZ);                            \
    hd_[OFF] = (short)pkbf(hv_, hv_);                                   \
} while (0)

#define MFMA14(Ax, BX, Ay, BY)                                          \
    Ax = mfma16(a0, BX##_0, Ax); Ay = mfma16(a0, BY##_0, Ay);           \
    Ax = mfma16(a1, BX##_1, Ax); Ay = mfma16(a1, BY##_1, Ay);           \
    Ax = mfma16(a2, BX##_2, Ax); Ay = mfma16(a2, BY##_2, Ay);           \
    Ax = mfma16(a3, BX##_3, Ax); Ay = mfma16(a3, BY##_3, Ay);           \
    Ax = mfma16(a4, BX##_4, Ax); Ay = mfma16(a4, BY##_4, Ay);           \
    Ax = mfma16(a5, BX##_5, Ax); Ay = mfma16(a5, BY##_5, Ay);           \
    Ax = mfma16(a6, BX##_6, Ax); Ay = mfma16(a6, BY##_6, Ay);

// One timestep. SUB: compile-time 0..7 (parity = SUB&1). PREF/XST: uniform
// runtime bools. FRZ: freeze (only sub 0 of group 0 passes non-false).
#define STEPB(SUB, PREF, XST, FRZ) do {                                 \
    if (PREF) {                                                         \
        xr0 = *(const float4*)(xp);                                     \
        xr1 = *(const float4*)(xp + 16);                                \
    }                                                                   \
    const short* haS_ = ((SUB) & 1) ? haB : haA;                        \
    const short* hcS_ = ((SUB) & 1) ? hcB : hcA;                        \
    short* hd_ = (((SUB) & 1) == 0) ? hw1 : hw0;                        \
    const bf16x8 a0 = *(const bf16x8*)(xbR + (SUB) * 640);              \
    const bf16x8 a1 = *(const bf16x8*)(haS_ + oH1);                     \
    const bf16x8 a2 = *(const bf16x8*)(haS_ + oH1 + 32);                \
    const bf16x8 a3 = *(const bf16x8*)(haS_ + oH2);                     \
    const bf16x8 a4 = *(const bf16x8*)(haS_ + oH2 + 32);                \
    const bf16x8 a5 = *(const bf16x8*)(hcS_ + oH2);                     \
    const bf16x8 a6 = *(const bf16x8*)(hcS_ + oH2 + 32);                \
    f32x4 A0 = {b0, b0, b0, b0}, A1 = {b1, b1, b1, b1},                 \
          A2 = {b2, b2, b2, b2}, A3 = {b3, b3, b3, b3};                 \
    MFMA14(A0, B0, A1, B1)                                              \
    ACT_STORE(A0, c0, 0, FRZ);                                          \
    MFMA14(A2, B2, A3, B3)                                              \
    ACT_STORE(A1, c1, 4, FRZ);                                          \
    ACT_STORE(A2, c2, 8, FRZ);                                          \
    ACT_STORE(A3, c3, 12, FRZ);                                         \
    if (XST) {                                                          \
        short4v pa_; pa_[0] = f2bf(xr0.x); pa_[1] = f2bf(xr0.y);        \
        pa_[2] = f2bf(xr0.z); pa_[3] = f2bf(xr0.w);                     \
        *(short4v*)(xsW) = pa_;                                         \
        short4v pb_; pb_[0] = f2bf(xr1.x); pb_[1] = f2bf(xr1.y);        \
        pb_[2] = f2bf(xr1.z); pb_[3] = f2bf(xr1.w);                     \
        *(short4v*)(xsW + 16) = pb_;                                    \
    }                                                                   \
    __syncthreads();                                                    \
} while (0)

__global__ __launch_bounds__(256)
void lstm_mfma_68547678044465(const float* __restrict__ x,
                              const float* __restrict__ Wih0, const float* __restrict__ Whh0,
                              const float* __restrict__ bih0, const float* __restrict__ bhh0,
                              const float* __restrict__ Wih1, const float* __restrict__ Whh1,
                              const float* __restrict__ bih1, const float* __restrict__ bhh1,
                              const float* __restrict__ ln_g, const float* __restrict__ ln_b,
                              const float* __restrict__ fcw, const float* __restrict__ fcb,
                              float* __restrict__ out)
{
    __shared__ __align__(16) short XB[2][8][16][40];  // x bf16; rows 8-15 always zero
    __shared__ __align__(16) short HA[2][24][72];     // rows 0-7 zero | 8-15 h0 | 16-23 zero
    __shared__ __align__(16) short HC[2][16][72];     // rows 0-7 zero | 8-15 h1
    __shared__ __align__(16) float HF[8][64];         // final h1 fp32 for LN

    const int tid  = threadIdx.x;
    const int wl   = tid >> 6;           // wave 0..3
    const int lane = tid & 63;
    const int n    = lane & 15;          // A row m / C col n
    const int q    = lane >> 4;          // k-quad / C row group
    const int wg   = n & 3;              // this column's gate (0=i 1=f 2=g 3=o)
    const int cs   = n >> 2;             // cell-within-subtile
    const int rb   = blockIdx.x * RPB;
    const bool qhi = (q >= 2);
    const bool s1  = (lane & 1) != 0;
    const bool s2  = (lane & 2) != 0;

    // weight rows for this lane's column in sub-tiles 0..3 (cell = wcell+4t)
    const int wcell = wl * 16 + cs;
    const float sc  = (wg == 2) ? L2E2 : L2E;
    const int wr0 = wg * 64 + wcell;
    const int wr1 = wr0 + 4, wr2 = wr0 + 8, wr3 = wr0 + 12;

    // ---- B-fragments: 4 cell-subtiles x 7 K-chunks, named registers ----
    auto loadB = [&](const float* wrow) -> bf16x8 {
        const float4 lo = *(const float4*)(wrow);
        const float4 hi = *(const float4*)(wrow + 4);
        short8 r;
        r[0] = f2bf(lo.x * sc); r[1] = f2bf(lo.y * sc);
        r[2] = f2bf(lo.z * sc); r[3] = f2bf(lo.w * sc);
        r[4] = f2bf(hi.x * sc); r[5] = f2bf(hi.y * sc);
        r[6] = f2bf(hi.z * sc); r[7] = f2bf(hi.w * sc);
        return (bf16x8)r;
    };
    const int ko = q * 8;
    const bf16x8 B0_0 = loadB(Wih0 + wr0 * 32 + ko);
    const bf16x8 B0_1 = loadB(Whh0 + wr0 * 64 + ko);
    const bf16x8 B0_2 = loadB(Whh0 + wr0 * 64 + 32 + ko);
    const bf16x8 B0_3 = loadB(Wih1 + wr0 * 64 + ko);
    const bf16x8 B0_4 = loadB(Wih1 + wr0 * 64 + 32 + ko);
    const bf16x8 B0_5 = loadB(Whh1 + wr0 * 64 + ko);
    const bf16x8 B0_6 = loadB(Whh1 + wr0 * 64 + 32 + ko);
    const bf16x8 B1_0 = loadB(Wih0 + wr1 * 32 + ko);
    const bf16x8 B1_1 = loadB(Whh0 + wr1 * 64 + ko);
    const bf16x8 B1_2 = loadB(Whh0 + wr1 * 64 + 32 + ko);
    const bf16x8 B1_3 = loadB(Wih1 + wr1 * 64 + ko);
    const bf16x8 B1_4 = loadB(Wih1 + wr1 * 64 + 32 + ko);
    const bf16x8 B1_5 = loadB(Whh1 + wr1 * 64 + ko);
    const bf16x8 B1_6 = loadB(Whh1 + wr1 * 64 + 32 + ko);
    const bf16x8 B2_0 = loadB(Wih0 + wr2 * 32 + ko);
    const bf16x8 B2_1 = loadB(Whh0 + wr2 * 64 + ko);
    const bf16x8 B2_2 = loadB(Whh0 + wr2 * 64 + 32 + ko);
    const bf16x8 B2_3 = loadB(Wih1 + wr2 * 64 + ko);
    const bf16x8 B2_4 = loadB(Wih1 + wr2 * 64 + 32 + ko);
    const bf16x8 B2_5 = loadB(Whh1 + wr2 * 64 + ko);
    const bf16x8 B2_6 = loadB(Whh1 + wr2 * 64 + 32 + ko);
    const bf16x8 B3_0 = loadB(Wih0 + wr3 * 32 + ko);
    const bf16x8 B3_1 = loadB(Whh0 + wr3 * 64 + ko);
    const bf16x8 B3_2 = loadB(Whh0 + wr3 * 64 + 32 + ko);
    const bf16x8 B3_3 = loadB(Wih1 + wr3 * 64 + ko);
    const bf16x8 B3_4 = loadB(Wih1 + wr3 * 64 + 32 + ko);
    const bf16x8 B3_5 = loadB(Whh1 + wr3 * 64 + ko);
    const bf16x8 B3_6 = loadB(Whh1 + wr3 * 64 + 32 + ko);

    // ---- biases: per-lane layer select (q<2 -> L0 rows, q>=2 -> L1 rows) ----
    float b0, b1, b2, b3;
    if (!qhi) {
        b0 = (bih0[wr0] + bhh0[wr0]) * sc; b1 = (bih0[wr1] + bhh0[wr1]) * sc;
        b2 = (bih0[wr2] + bhh0[wr2]) * sc; b3 = (bih0[wr3] + bhh0[wr3]) * sc;
    } else {
        b0 = (bih1[wr0] + bhh1[wr0]) * sc; b1 = (bih1[wr1] + bhh1[wr1]) * sc;
        b2 = (bih1[wr2] + bhh1[wr2]) * sc; b3 = (bih1[wr3] + bhh1[wr3]) * sc;
    }

    // ---- zero all LDS (zero rows must stay zero; parity bufs start 0) ----
    { int* z = (int*)XB; for (int i = tid; i < 5120; i += 256) z[i] = 0; }
    { int* z = (int*)HA; for (int i = tid; i < 1728; i += 256) z[i] = 0; }
    { int* z = (int*)HC; for (int i = tid; i < 1152; i += 256) z[i] = 0; }

    // ---- per-lane invariant LDS pointers / offsets (reads unchanged) ----
    const short* haA = &HA[0][0][0];
    const short* haB = &HA[1][0][0];
    const short* hcA = &HC[0][0][0];
    const short* hcB = &HC[1][0][0];
    const int oH1 = (8 + n) * 72 + q * 8;     // h0 rows 8+m (L0 side)
    const int oH2 = n * 72 + q * 8;           // rows m (zero pad | data)
    const short* xb0 = &XB[0][0][0][0] + (n * 40 + q * 8);
    const short* xb1 = xb0 + 5120;
    // write target: lane owns row 4q+wg (batch row (q&1)*4+wg of its layer),
    // cell wcell + 4t -> offset 4t shorts from the base below
    const int hrow = 8 + (q & 1) * 4 + wg;
    short* hw0 = (qhi ? &HC[0][hrow][0] : &HA[0][hrow][0]) + wcell;
    short* hw1 = (qhi ? &HC[1][hrow][0] : &HA[1][hrow][0]) + wcell;

    // ---- x staging: thread -> (step ss, row sm, quad kq), 2 float4 each ----
    const int ss = tid >> 5, sm = (tid >> 2) & 7, kq = tid & 3;
    const float* xrow = x + (size_t)(rb + sm) * (TSTEPS * 32);
    short* xs0 = &XB[0][ss][sm][0] + kq * 4;
    short* xs1 = xs0 + 5120;
    const float* xp = xrow + (8 + ss) * 32 + kq * 4;   // group-1 prefetch base
    float4 xr0 = *(const float4*)(xrow + ss * 32 + kq * 4);
    float4 xr1 = *(const float4*)(xrow + ss * 32 + kq * 4 + 16);
    {   // initial stage of group 0 into buf 0
        short4v pa; pa[0] = f2bf(xr0.x); pa[1] = f2bf(xr0.y);
        pa[2] = f2bf(xr0.z); pa[3] = f2bf(xr0.w);
        *(short4v*)(xs0) = pa;
        short4v pb; pb[0] = f2bf(xr1.x); pb[1] = f2bf(xr1.y);
        pb[2] = f2bf(xr1.z); pb[3] = f2bf(xr1.w);
        *(short4v*)(xs0 + 16) = pb;
    }
    __syncthreads();

    float c0 = 0.0f, c1 = 0.0f, c2 = 0.0f, c3 = 0.0f;

    // transpose own sub-tile's C within quads, then LSTM cell update.
    // In: V[r] = preact of (gate = this lane's col-gate, row 4q+r).
    // Out: this lane holds all 4 gates of row 4q+(lane&3) -> h value.
    auto actTile = [&](const f32x4& V, float& c, bool frz) -> float {
        const float r0 = V[0], r1 = V[1], r2 = V[2], r3 = V[3];
        const float t0 = s2 ? r0 : r2, t1 = s2 ? r1 : r3;
        const float u0 = dpp4<0x4E>(t0), u1 = dpp4<0x4E>(t1);
        const float e0 = s2 ? u0 : r0, e1 = s2 ? u1 : r1;
        const float e2 = s2 ? r2 : u0, e3 = s2 ? r3 : u1;
        const float p0 = s1 ? e0 : e1; const float g0 = dpp4<0xB1>(p0);
        const float wi = s1 ? g0 : e0;
        const float wf = s1 ? e1 : g0;
        const float p1 = s1 ? e2 : e3; const float g1 = dpp4<0xB1>(p1);
        const float wgv = s1 ? g1 : e2;
        const float wo  = s1 ? e3 : g1;
        const float iv = sigm_p(wi), fv = sigm_p(wf);
        const float gv = tanh_p(wgv), ov = sigm_p(wo);
        const float cn = fmaf(fv, c, iv * gv);
        c = frz ? 0.0f : cn;
        return ov * tanh_p(c * L2E2);          // exact 0 when frozen
    };

#pragma unroll 1
    for (int g = 0; g < 64; ++g) {
        const short* xbR = (g & 1) ? xb1 : xb0;   // read buf = g&1
        short* xsW       = (g & 1) ? xs0 : xs1;   // stage target = (g+1)&1
        const bool fz = (g == 0) && qhi;          // phantom L1 step -1
        const bool pg = (g < 63);
        STEPB(0, pg, 0, fz);
        STEPB(1, 0, 0, false);
        STEPB(2, 0, 0, false);
        STEPB(3, 0, 0, false);
        STEPB(4, 0, 0, false);
        STEPB(5, 0, 0, false);
        STEPB(6, 0, pg, false);
        STEPB(7, 0, 0, false);
        xp += 256;                                // next group's prefetch base
    }

    // ---- peeled epilogue step (it = TSTEPS): only L1 (q>=2) results used.
    // Rows 0-7 read stale XB data (finite garbage) -> L0 lanes' values unused.
    {
        const bf16x8 a0 = *(const bf16x8*)(xb0);
        const bf16x8 a1 = *(const bf16x8*)(haA + oH1);
        const bf16x8 a2 = *(const bf16x8*)(haA + oH1 + 32);
        const bf16x8 a3 = *(const bf16x8*)(haA + oH2);
        const bf16x8 a4 = *(const bf16x8*)(haA + oH2 + 32);
        const bf16x8 a5 = *(const bf16x8*)(hcA + oH2);
        const bf16x8 a6 = *(const bf16x8*)(hcA + oH2 + 32);
        f32x4 A0 = {b0, b0, b0, b0}, A1 = {b1, b1, b1, b1},
              A2 = {b2, b2, b2, b2}, A3 = {b3, b3, b3, b3};
        MFMA14(A0, B0, A1, B1)
        MFMA14(A2, B2, A3, B3)
        const float hv0 = actTile(A0, c0, false);
        const float hv1 = actTile(A1, c1, false);
        const float hv2 = actTile(A2, c2, false);
        const float hv3 = actTile(A3, c3, false);
        if (qhi) {                              // final h1 (step T-1), fp32
            const int hr = (q & 1) * 4 + wg;
            HF[hr][wcell + 0]  = hv0;
            HF[hr][wcell + 4]  = hv1;
            HF[hr][wcell + 8]  = hv2;
            HF[hr][wcell + 12] = hv3;
        }
    }
    __syncthreads();

    // ---- epilogue: LayerNorm + FC; each wave handles 2 rows ----
    const float lg = ln_g[lane], lb = ln_b[lane], fw = fcw[lane], fb = fcb[0];
#pragma unroll
    for (int rr = 0; rr < 2; ++rr) {
        const int row = wl * 2 + rr;
        const float v = HF[row][lane];
        float s1r = v, sqr = v * v;
#pragma unroll
        for (int mm = 1; mm < 64; mm <<= 1) {
            s1r += __shfl_xor(s1r, mm, 64);
            sqr += __shfl_xor(sqr, mm, 64);
        }
        const float mu = s1r * (1.0f / 64.0f);
        float var = sqr * (1.0f / 64.0f) - mu * mu;
        var = fmaxf(var, 0.0f);
        const float rs = rsqrtf(var + 1e-5f);
        float pv = ((v - mu) * rs * lg + lb) * fw;
#pragma unroll
        for (int mm = 1; mm < 64; mm <<= 1) pv += __shfl_xor(pv, mm, 64);
        if (lane == 0) out[rb + row] = pv + fb;
    }
}

extern "C" void kernel_launch(void* const* d_in, const int* in_sizes, int n_in,
                              void* d_out, int out_size, void* d_ws, size_t ws_size,
                              hipStream_t stream) {
    const float* x    = (const float*)d_in[0];
    const float* Wih0 = (const float*)d_in[1];
    const float* Whh0 = (const float*)d_in[2];
    const float* bih0 = (const float*)d_in[3];
    const float* bhh0 = (const float*)d_in[4];
    const float* Wih1 = (const float*)d_in[5];
    const float* Whh1 = (const float*)d_in[6];
    const float* bih1 = (const float*)d_in[7];
    const float* bhh1 = (const float*)d_in[8];
    const float* ln_g = (const float*)d_in[9];
    const float* ln_b = (const float*)d_in[10];
    const float* fcw  = (const float*)d_in[11];
    const float* fcb  = (const float*)d_in[12];

    dim3 grid(2048 / RPB);    // 256 blocks -> 1 per CU
    dim3 block(256);          // 4 waves: 1 per SIMD
    hipLaunchKernelGGL(lstm_mfma_68547678044465, grid, block, 0, stream,
                       x, Wih0, Whh0, bih0, bhh0, Wih1, Whh1, bih1, bhh1,
                       ln_g, ln_b, fcw, fcb, (float*)d_out);
}

// Round 4
// 446.663 us; speedup vs baseline: 1.1466x; 1.1466x over previous
//
#include <hip/hip_runtime.h>
#include <math.h>

#define TSTEPS 512
#define RPB 8
#define L2E  1.4426950408889634f
#define L2E2 2.8853900817779268f   // 2*log2(e)

typedef __attribute__((ext_vector_type(4))) short short4v;
typedef __attribute__((ext_vector_type(8))) short short8;
typedef __attribute__((ext_vector_type(4))) float f32x4;
typedef __bf16 bf16x8 __attribute__((ext_vector_type(8)));

__device__ __forceinline__ short f2bf(float f) {            // RNE float->bf16
    union { float f; unsigned u; } v; v.f = f;
    return (short)((v.u + 0x7FFFu + ((v.u >> 16) & 1u)) >> 16);
}
__device__ __forceinline__ unsigned pkbf(float lo, float hi) {  // HW RNE pack
    unsigned r;
    asm("v_cvt_pk_bf16_f32 %0, %1, %2" : "=v"(r) : "v"(lo), "v"(hi));
    return r;
}
__device__ __forceinline__ float rcp_f(float x) { return __builtin_amdgcn_rcpf(x); }
__device__ __forceinline__ float ex2(float x)   { return __builtin_amdgcn_exp2f(x); }
__device__ __forceinline__ float sigm_p(float v) { return rcp_f(1.0f + ex2(-v)); }   // v = x*log2e
__device__ __forceinline__ float tanh_p(float v) {                                    // v = x*2log2e
    return fmaf(-2.0f, rcp_f(1.0f + ex2(v)), 1.0f);        // 1 - 2/(1+e^{2x})
}
__device__ __forceinline__ f32x4 mfma16(bf16x8 a, bf16x8 b, f32x4 c) {
    return __builtin_amdgcn_mfma_f32_16x16x32_bf16(a, b, c, 0, 0, 0);
}

// 256 blocks x 256 threads (4 waves, 1/SIMD). Both layers merged into ONE
// 16x16 MFMA tile via block-diagonal K-packing (K=224), A rows:
//   rows 0-7  = [x_t (32) | h0^{t-1} (64) | 0 (128)]        -> L0 step t
//   rows 8-15 = [0 (96)   | h0^{t-1} (64) | h1^{t-2} (64)]  -> L1 step t-1
// THIS ROUND (acc-major issue, zero added ops vs the 382us kernel):
//  * x-fragment a0c for step t is PRELOADED during step t-1 (its XB buffer
//    was written >=1 barrier earlier) -> the 4 x-chunk MFMAs issue at
//    barrier-exit with no lgkm dependence, covering the h ds_read latency.
//  * MFMAs issue as two acc-PAIR chains: (g,i) chunks 0..6, then (f,o).
//    g/i complete at the 50% mark; tanh(g), sigm(i), i*g execute under the
//    (f,o) MFMA window (separate pipes). Per-acc accumulation order is
//    unchanged (chunks 0..6) -> bit-identical results.
//  * tail: sigm(f), sigm(o), c-update, tanh(c), pack, 4x ds_write_b16.
#define STEPB(SUB, PREF, XST, FRZ, XNXT) do {                           \
    const short* haS_ = ((SUB) & 1) ? haB : haA;                        \
    const short* hcS_ = ((SUB) & 1) ? hcB : hcA;                        \
    const bf16x8 a1 = *(const bf16x8*)(haS_ + oH1);                     \
    const bf16x8 a2 = *(const bf16x8*)(haS_ + oH1 + 32);                \
    const bf16x8 a3 = *(const bf16x8*)(haS_ + oH2);                     \
    const bf16x8 a4 = *(const bf16x8*)(haS_ + oH2 + 32);                \
    const bf16x8 a5 = *(const bf16x8*)(hcS_ + oH2);                     \
    const bf16x8 a6 = *(const bf16x8*)(hcS_ + oH2 + 32);                \
    if (PREF) {                                                         \
        xr0 = *(const float4*)(xp);                                     \
        xr1 = *(const float4*)(xp + 16);                                \
    }                                                                   \
    f32x4 AG = {b2, b2, b2, b2}, AI = {b0, b0, b0, b0},                 \
          AF = {b1, b1, b1, b1}, AO = {b3, b3, b3, b3};                 \
    AG = mfma16(a0c, B2_0, AG); AI = mfma16(a0c, B0_0, AI);             \
    AF = mfma16(a0c, B1_0, AF); AO = mfma16(a0c, B3_0, AO);             \
    AG = mfma16(a1, B2_1, AG); AI = mfma16(a1, B0_1, AI);               \
    AG = mfma16(a2, B2_2, AG); AI = mfma16(a2, B0_2, AI);               \
    AG = mfma16(a3, B2_3, AG); AI = mfma16(a3, B0_3, AI);               \
    AG = mfma16(a4, B2_4, AG); AI = mfma16(a4, B0_4, AI);               \
    AG = mfma16(a5, B2_5, AG); AI = mfma16(a5, B0_5, AI);               \
    AG = mfma16(a6, B2_6, AG); AI = mfma16(a6, B0_6, AI);               \
    const float gv0 = tanh_p(AG[0]), gv1 = tanh_p(AG[1]);               \
    const float gv2 = tanh_p(AG[2]), gv3 = tanh_p(AG[3]);               \
    const float ig0 = sigm_p(AI[0]) * gv0, ig1 = sigm_p(AI[1]) * gv1;   \
    const float ig2 = sigm_p(AI[2]) * gv2, ig3 = sigm_p(AI[3]) * gv3;   \
    AF = mfma16(a1, B1_1, AF); AO = mfma16(a1, B3_1, AO);               \
    AF = mfma16(a2, B1_2, AF); AO = mfma16(a2, B3_2, AO);               \
    AF = mfma16(a3, B1_3, AF); AO = mfma16(a3, B3_3, AO);               \
    AF = mfma16(a4, B1_4, AF); AO = mfma16(a4, B3_4, AO);               \
    AF = mfma16(a5, B1_5, AF); AO = mfma16(a5, B3_5, AO);               \
    AF = mfma16(a6, B1_6, AF); AO = mfma16(a6, B3_6, AO);               \
    short* hd_ = (((SUB) & 1) == 0) ? hw1 : hw0;                        \
    float hv0, hv1, hv2, hv3;                                           \
    {                                                                   \
        const float fv_ = sigm_p(AF[0]), ov_ = sigm_p(AO[0]);           \
        const float cn_ = fmaf(fv_, c0, ig0);                           \
        c0 = (FRZ) ? 0.0f : cn_;                                        \
        hv0 = ov_ * tanh_p(c0 * L2E2);                                  \
    }                                                                   \
    {                                                                   \
        const float fv_ = sigm_p(AF[1]), ov_ = sigm_p(AO[1]);           \
        const float cn_ = fmaf(fv_, c1, ig1);                           \
        c1 = (FRZ) ? 0.0f : cn_;                                        \
        hv1 = ov_ * tanh_p(c1 * L2E2);                                  \
    }                                                                   \
    {                                                                   \
        const float fv_ = sigm_p(AF[2]), ov_ = sigm_p(AO[2]);           \
        const float cn_ = fmaf(fv_, c2, ig2);                           \
        c2 = (FRZ) ? 0.0f : cn_;                                        \
        hv2 = ov_ * tanh_p(c2 * L2E2);                                  \
    }                                                                   \
    {                                                                   \
        const float fv_ = sigm_p(AF[3]), ov_ = sigm_p(AO[3]);           \
        const float cn_ = fmaf(fv_, c3, ig3);                           \
        c3 = (FRZ) ? 0.0f : cn_;                                        \
        hv3 = ov_ * tanh_p(c3 * L2E2);                                  \
    }                                                                   \
    const unsigned pA_ = pkbf(hv0, hv1);                                \
    const unsigned pB_ = pkbf(hv2, hv3);                                \
    hd_[0]   = (short)pA_; hd_[72]  = (short)(pA_ >> 16);               \
    hd_[144] = (short)pB_; hd_[216] = (short)(pB_ >> 16);               \
    if (XST) {                                                          \
        short4v pa_; pa_[0] = f2bf(xr0.x); pa_[1] = f2bf(xr0.y);        \
        pa_[2] = f2bf(xr0.z); pa_[3] = f2bf(xr0.w);                     \
        *(short4v*)(xsW) = pa_;                                         \
        short4v pb_; pb_[0] = f2bf(xr1.x); pb_[1] = f2bf(xr1.y);        \
        pb_[2] = f2bf(xr1.z); pb_[3] = f2bf(xr1.w);                     \
        *(short4v*)(xsW + 16) = pb_;                                    \
    }                                                                   \
    a0c = *(const bf16x8*)(XNXT);   /* next step's x frag: buffer is stable */ \
    __syncthreads();                                                    \
} while (0)

__global__ __launch_bounds__(256)
void lstm_mfma_68547678044465(const float* __restrict__ x,
                              const float* __restrict__ Wih0, const float* __restrict__ Whh0,
                              const float* __restrict__ bih0, const float* __restrict__ bhh0,
                              const float* __restrict__ Wih1, const float* __restrict__ Whh1,
                              const float* __restrict__ bih1, const float* __restrict__ bhh1,
                              const float* __restrict__ ln_g, const float* __restrict__ ln_b,
                              const float* __restrict__ fcw, const float* __restrict__ fcb,
                              float* __restrict__ out)
{
    __shared__ __align__(16) short XB[2][8][16][40];  // x bf16; rows 8-15 always zero
    __shared__ __align__(16) short HA[2][24][72];     // rows 0-7 zero | 8-15 h0 | 16-23 zero
    __shared__ __align__(16) short HC[2][16][72];     // rows 0-7 zero | 8-15 h1
    __shared__ __align__(16) float HF[8][64];         // final h1 fp32 for LN

    const int tid  = threadIdx.x;
    const int wl   = tid >> 6;           // wave 0..3
    const int lane = tid & 63;
    const int n    = lane & 15;          // A row m / C col n
    const int q    = lane >> 4;          // k-quad / C row group
    const int rb   = blockIdx.x * RPB;
    const int cell = wl * 16 + n;        // h-dim cell 0..63
    const bool qhi = (q >= 2);

    // ---- B-fragments: 4 gate-tiles x 7 K-chunks, named registers ----
    auto loadB = [&](const float* wrow, float sc) -> bf16x8 {
        const float4 lo = *(const float4*)(wrow);
        const float4 hi = *(const float4*)(wrow + 4);
        short8 r;
        r[0] = f2bf(lo.x * sc); r[1] = f2bf(lo.y * sc);
        r[2] = f2bf(lo.z * sc); r[3] = f2bf(lo.w * sc);
        r[4] = f2bf(hi.x * sc); r[5] = f2bf(hi.y * sc);
        r[6] = f2bf(hi.z * sc); r[7] = f2bf(hi.w * sc);
        return (bf16x8)r;
    };
    const int g0 = cell, g1 = 64 + cell, g2 = 128 + cell, g3 = 192 + cell;
    const int ko = q * 8;
    const bf16x8 B0_0 = loadB(Wih0 + g0 * 32 + ko, L2E);
    const bf16x8 B0_1 = loadB(Whh0 + g0 * 64 + ko, L2E);
    const bf16x8 B0_2 = loadB(Whh0 + g0 * 64 + 32 + ko, L2E);
    const bf16x8 B0_3 = loadB(Wih1 + g0 * 64 + ko, L2E);
    const bf16x8 B0_4 = loadB(Wih1 + g0 * 64 + 32 + ko, L2E);
    const bf16x8 B0_5 = loadB(Whh1 + g0 * 64 + ko, L2E);
    const bf16x8 B0_6 = loadB(Whh1 + g0 * 64 + 32 + ko, L2E);
    const bf16x8 B1_0 = loadB(Wih0 + g1 * 32 + ko, L2E);
    const bf16x8 B1_1 = loadB(Whh0 + g1 * 64 + ko, L2E);
    const bf16x8 B1_2 = loadB(Whh0 + g1 * 64 + 32 + ko, L2E);
    const bf16x8 B1_3 = loadB(Wih1 + g1 * 64 + ko, L2E);
    const bf16x8 B1_4 = loadB(Wih1 + g1 * 64 + 32 + ko, L2E);
    const bf16x8 B1_5 = loadB(Whh1 + g1 * 64 + ko, L2E);
    const bf16x8 B1_6 = loadB(Whh1 + g1 * 64 + 32 + ko, L2E);
    const bf16x8 B2_0 = loadB(Wih0 + g2 * 32 + ko, L2E2);
    const bf16x8 B2_1 = loadB(Whh0 + g2 * 64 + ko, L2E2);
    const bf16x8 B2_2 = loadB(Whh0 + g2 * 64 + 32 + ko, L2E2);
    const bf16x8 B2_3 = loadB(Wih1 + g2 * 64 + ko, L2E2);
    const bf16x8 B2_4 = loadB(Wih1 + g2 * 64 + 32 + ko, L2E2);
    const bf16x8 B2_5 = loadB(Whh1 + g2 * 64 + ko, L2E2);
    const bf16x8 B2_6 = loadB(Whh1 + g2 * 64 + 32 + ko, L2E2);
    const bf16x8 B3_0 = loadB(Wih0 + g3 * 32 + ko, L2E);
    const bf16x8 B3_1 = loadB(Whh0 + g3 * 64 + ko, L2E);
    const bf16x8 B3_2 = loadB(Whh0 + g3 * 64 + 32 + ko, L2E);
    const bf16x8 B3_3 = loadB(Wih1 + g3 * 64 + ko, L2E);
    const bf16x8 B3_4 = loadB(Wih1 + g3 * 64 + 32 + ko, L2E);
    const bf16x8 B3_5 = loadB(Whh1 + g3 * 64 + ko, L2E);
    const bf16x8 B3_6 = loadB(Whh1 + g3 * 64 + 32 + ko, L2E);

    // ---- biases: per-lane layer select (q<2 -> L0 rows, q>=2 -> L1 rows) ----
    float b0, b1, b2, b3;
    if (!qhi) {
        b0 = (bih0[g0] + bhh0[g0]) * L2E;  b1 = (bih0[g1] + bhh0[g1]) * L2E;
        b2 = (bih0[g2] + bhh0[g2]) * L2E2; b3 = (bih0[g3] + bhh0[g3]) * L2E;
    } else {
        b0 = (bih1[g0] + bhh1[g0]) * L2E;  b1 = (bih1[g1] + bhh1[g1]) * L2E;
        b2 = (bih1[g2] + bhh1[g2]) * L2E2; b3 = (bih1[g3] + bhh1[g3]) * L2E;
    }

    // ---- zero all LDS (zero rows must stay zero; parity bufs start 0) ----
    { int* z = (int*)XB; for (int i = tid; i < 5120; i += 256) z[i] = 0; }
    { int* z = (int*)HA; for (int i = tid; i < 1728; i += 256) z[i] = 0; }
    { int* z = (int*)HC; for (int i = tid; i < 1152; i += 256) z[i] = 0; }

    // ---- per-lane invariant LDS pointers / offsets ----
    const short* haA = &HA[0][0][0];
    const short* haB = &HA[1][0][0];
    const short* hcA = &HC[0][0][0];
    const short* hcB = &HC[1][0][0];
    const int oH1 = (8 + n) * 72 + q * 8;     // h0 rows 8+m (L0 side)
    const int oH2 = n * 72 + q * 8;           // rows m (zero pad | data)
    const short* xb0 = &XB[0][0][0][0] + (n * 40 + q * 8);
    const short* xb1 = xb0 + 5120;
    short* hw0 = (qhi ? &HC[0][8 + (q & 1) * 4][0]
                      : &HA[0][8 + (q & 1) * 4][0]) + cell;   // parity-0 target
    short* hw1 = (qhi ? &HC[1][8 + (q & 1) * 4][0]
                      : &HA[1][8 + (q & 1) * 4][0]) + cell;   // parity-1 target

    // ---- x staging: thread -> (step ss, row sm, quad kq), 2 float4 each ----
    const int ss = tid >> 5, sm = (tid >> 2) & 7, kq = tid & 3;
    const float* xrow = x + (size_t)(rb + sm) * (TSTEPS * 32);
    short* xs0 = &XB[0][ss][sm][0] + kq * 4;
    short* xs1 = xs0 + 5120;
    const float* xp = xrow + (8 + ss) * 32 + kq * 4;   // group-1 prefetch base
    float4 xr0 = *(const float4*)(xrow + ss * 32 + kq * 4);
    float4 xr1 = *(const float4*)(xrow + ss * 32 + kq * 4 + 16);
    {   // initial stage of group 0 into buf 0
        short4v pa; pa[0] = f2bf(xr0.x); pa[1] = f2bf(xr0.y);
        pa[2] = f2bf(xr0.z); pa[3] = f2bf(xr0.w);
        *(short4v*)(xs0) = pa;
        short4v pb; pb[0] = f2bf(xr1.x); pb[1] = f2bf(xr1.y);
        pb[2] = f2bf(xr1.z); pb[3] = f2bf(xr1.w);
        *(short4v*)(xs0 + 16) = pb;
    }
    __syncthreads();

    float c0 = 0.0f, c1 = 0.0f, c2 = 0.0f, c3 = 0.0f;
    bf16x8 a0c = *(const bf16x8*)(xb0);       // x frag for step 0

#pragma unroll 1
    for (int g = 0; g < 64; ++g) {
        const short* xbR = (g & 1) ? xb1 : xb0;   // read buf = g&1
        const short* xbO = (g & 1) ? xb0 : xb1;   // other buf (next group)
        short* xsW       = (g & 1) ? xs0 : xs1;   // stage target = (g+1)&1
        const bool fz = (g == 0) && qhi;          // phantom L1 step -1
        const bool pg = (g < 63);
        STEPB(0, pg, 0, fz,    xbR + 640);
        STEPB(1, 0, 0, false,  xbR + 1280);
        STEPB(2, 0, 0, false,  xbR + 1920);
        STEPB(3, 0, 0, false,  xbR + 2560);
        STEPB(4, 0, 0, false,  xbR + 3200);
        STEPB(5, 0, 0, false,  xbR + 3840);
        STEPB(6, 0, pg, false, xbR + 4480);
        STEPB(7, 0, 0, false,  xbO);
        xp += 256;                                // next group's prefetch base
    }

    // ---- peeled epilogue step (it = TSTEPS): only L1 (q>=2) results used.
    // a0c holds stale buf-0 x data (finite garbage) -> L0 lanes' values unused.
    {
        const bf16x8 a1 = *(const bf16x8*)(haA + oH1);
        const bf16x8 a2 = *(const bf16x8*)(haA + oH1 + 32);
        const bf16x8 a3 = *(const bf16x8*)(haA + oH2);
        const bf16x8 a4 = *(const bf16x8*)(haA + oH2 + 32);
        const bf16x8 a5 = *(const bf16x8*)(hcA + oH2);
        const bf16x8 a6 = *(const bf16x8*)(hcA + oH2 + 32);
        f32x4 AG = {b2, b2, b2, b2}, AI = {b0, b0, b0, b0},
              AF = {b1, b1, b1, b1}, AO = {b3, b3, b3, b3};
        AG = mfma16(a0c, B2_0, AG); AI = mfma16(a0c, B0_0, AI);
        AF = mfma16(a0c, B1_0, AF); AO = mfma16(a0c, B3_0, AO);
        AG = mfma16(a1, B2_1, AG); AI = mfma16(a1, B0_1, AI);
        AG = mfma16(a2, B2_2, AG); AI = mfma16(a2, B0_2, AI);
        AG = mfma16(a3, B2_3, AG); AI = mfma16(a3, B0_3, AI);
        AG = mfma16(a4, B2_4, AG); AI = mfma16(a4, B0_4, AI);
        AG = mfma16(a5, B2_5, AG); AI = mfma16(a5, B0_5, AI);
        AG = mfma16(a6, B2_6, AG); AI = mfma16(a6, B0_6, AI);
        AF = mfma16(a1, B1_1, AF); AO = mfma16(a1, B3_1, AO);
        AF = mfma16(a2, B1_2, AF); AO = mfma16(a2, B3_2, AO);
        AF = mfma16(a3, B1_3, AF); AO = mfma16(a3, B3_3, AO);
        AF = mfma16(a4, B1_4, AF); AO = mfma16(a4, B3_4, AO);
        AF = mfma16(a5, B1_5, AF); AO = mfma16(a5, B3_5, AO);
        AF = mfma16(a6, B1_6, AF); AO = mfma16(a6, B3_6, AO);
        const float gv0 = tanh_p(AG[0]), gv1 = tanh_p(AG[1]);
        const float gv2 = tanh_p(AG[2]), gv3 = tanh_p(AG[3]);
        const float ig0 = sigm_p(AI[0]) * gv0, ig1 = sigm_p(AI[1]) * gv1;
        const float ig2 = sigm_p(AI[2]) * gv2, ig3 = sigm_p(AI[3]) * gv3;
        float hv0, hv1, hv2, hv3;
        {
            const float fv_ = sigm_p(AF[0]), ov_ = sigm_p(AO[0]);
            c0 = fmaf(fv_, c0, ig0); hv0 = ov_ * tanh_p(c0 * L2E2);
        }
        {
            const float fv_ = sigm_p(AF[1]), ov_ = sigm_p(AO[1]);
            c1 = fmaf(fv_, c1, ig1); hv1 = ov_ * tanh_p(c1 * L2E2);
        }
        {
            const float fv_ = sigm_p(AF[2]), ov_ = sigm_p(AO[2]);
            c2 = fmaf(fv_, c2, ig2); hv2 = ov_ * tanh_p(c2 * L2E2);
        }
        {
            const float fv_ = sigm_p(AF[3]), ov_ = sigm_p(AO[3]);
            c3 = fmaf(fv_, c3, ig3); hv3 = ov_ * tanh_p(c3 * L2E2);
        }
        if (qhi) {                              // final h1 (step T-1), fp32
            const int rl = (q & 1) * 4;
            HF[rl + 0][cell] = hv0;
            HF[rl + 1][cell] = hv1;
            HF[rl + 2][cell] = hv2;
            HF[rl + 3][cell] = hv3;
        }
    }
    __syncthreads();

    // ---- epilogue: LayerNorm + FC; each wave handles 2 rows ----
    const float lg = ln_g[lane], lb = ln_b[lane], fw = fcw[lane], fb = fcb[0];
#pragma unroll
    for (int rr = 0; rr < 2; ++rr) {
        const int row = wl * 2 + rr;
        const float v = HF[row][lane];
        float s1 = v, sq = v * v;
#pragma unroll
        for (int mm = 1; mm < 64; mm <<= 1) {
            s1 += __shfl_xor(s1, mm, 64);
            sq += __shfl_xor(sq, mm, 64);
        }
        const float mu = s1 * (1.0f / 64.0f);
        float var = sq * (1.0f / 64.0f) - mu * mu;
        var = fmaxf(var, 0.0f);
        const float rs = rsqrtf(var + 1e-5f);
        float pv = ((v - mu) * rs * lg + lb) * fw;
#pragma unroll
        for (int mm = 1; mm < 64; mm <<= 1) pv += __shfl_xor(pv, mm, 64);
        if (lane == 0) out[rb + row] = pv + fb;
    }
}

extern "C" void kernel_launch(void* const* d_in, const int* in_sizes, int n_in,
                              void* d_out, int out_size, void* d_ws, size_t ws_size,
                              hipStream_t stream) {
    const float* x    = (const float*)d_in[0];
    const float* Wih0 = (const float*)d_in[1];
    const float* Whh0 = (const float*)d_in[2];
    const float* bih0 = (const float*)d_in[3];
    const float* bhh0 = (const float*)d_in[4];
    const float* Wih1 = (const float*)d_in[5];
    const float* Whh1 = (const float*)d_in[6];
    const float* bih1 = (const float*)d_in[7];
    const float* bhh1 = (const float*)d_in[8];
    const float* ln_g = (const float*)d_in[9];
    const float* ln_b = (const float*)d_in[10];
    const float* fcw  = (const float*)d_in[11];
    const float* fcb  = (const float*)d_in[12];

    dim3 grid(2048 / RPB);    // 256 blocks -> 1 per CU
    dim3 block(256);          // 4 waves: 1 per SIMD
    hipLaunchKernelGGL(lstm_mfma_68547678044465, grid, block, 0, stream,
                       x, Wih0, Whh0, bih0, bhh0, Wih1, Whh1, bih1, bhh1,
                       ln_g, ln_b, fcw, fcb, (float*)d_out);
}